// Round 14
// baseline (190.747 us; speedup 1.0000x reference)
//
#include <hip/hip_runtime.h>
#include <math.h>

#define NB 4096     // B (producer blocks)
#define LL 200      // L
#define EE 50       // E
#define CH 104      // gather chunk-1 length (13*8); chunk-2 = 96
#define CP 105      // chunk tile stride in words (odd -> spread banks)
#define NT 512      // threads per block (8 waves)
#define GG 8        // lanes per feature group
#define IT 25       // items per lane in registers
#define IT1 13      // chunk-1 covers t in [0,13)
#define SW 8        // small-set threshold
#define K2B 256     // consumer blocks
#define BPB 16      // batches per consumer block (2 reps x 8 waves)

__device__ int g_done[K2B];   // per-consumer-group producer counters

// monotonic float -> sortable uint32 (order-preserving bijection)
__device__ __forceinline__ unsigned f2key(float f) {
    unsigned b = __float_as_uint(f);
    unsigned mask = (b & 0x80000000u) ? 0xFFFFFFFFu : 0x80000000u;
    return b ^ mask;
}
__device__ __forceinline__ float key2f(unsigned kk) {
    unsigned mask = (kk & 0x80000000u) ? 0x80000000u : 0xFFFFFFFFu;
    return __uint_as_float(kk ^ mask);
}

struct ProdS {                      // 24.4 KB
    unsigned wK[EE][CP];
    int      idxL[LL];
    float    ratL[LL];
    unsigned sbuf[EE][SW];
    int      scnt[EE];
};
struct ConsS {                      // 28.9 KB
    float W2s[2*EE*EE];
    float b1s[2*EE];
    float b2s[EE];
    float W3s[EE];
    float xs[8][252];
};

// exact interpolation-select (invariant: cLO=#{x<LO} <= k < cHI=#{x<HI})
__device__ __forceinline__ unsigned select_median(
    int n, int k, int g, int grp, const unsigned it[IT],
    unsigned kmin, unsigned kmax, unsigned (*sbuf)[SW], int *scnt)
{
    unsigned LO = kmin, HI = kmax + 1u;   // finite keys: no wrap
    int cLO = 0, cHI = n;
    unsigned med = 0u;
    bool small = false;
    int pass = 0;
    for (;;) {
        if (HI - LO == 1u) { med = LO; break; }   // window collapsed
        const int w = cHI - cLO;
        if (w <= SW) { small = true; break; }
        unsigned P;
        if (pass < 8) {            // float-space interpolation pivot
            const float vlo = key2f(LO);
            const float vhi = key2f(HI - 1u);
            const float frac = (float)(k - cLO + 1) / (float)(w + 1);
            P = f2key(vlo + (vhi - vlo) * frac);
        } else {                   // guaranteed-progress bisection
            P = LO + ((HI - LO) >> 1);
        }
        if (P <= LO) P = LO + 1u;  // strict interior: interval shrinks
        if (P >= HI) P = HI - 1u;
        int c = 0;                 // #{x < P}; sentinels never count
        #pragma unroll
        for (int t = 0; t < IT; t++) c += (it[t] < P) ? 1 : 0;
        c += __shfl_xor(c, 1);
        c += __shfl_xor(c, 2);
        c += __shfl_xor(c, 4);
        if (c > k) { HI = P; cHI = c; }
        else       { LO = P; cLO = c; }
        pass++;
    }
    if (small) {
        const int w = cHI - cLO;   // #survivors, <= SW
        const int r = k - cLO;     // target rank among survivors
        #pragma unroll
        for (int t = 0; t < IT; t++) {
            const unsigned kk = it[t];
            if (kk >= LO && kk < HI) {
                const int pos = atomicAdd(&scnt[grp], 1);
                if (pos < SW) sbuf[grp][pos] = kk;
            }
        }
        // same-wave LDS ordering: compiler lgkmcnt waits cover these reads
        const unsigned sv = (g < w) ? sbuf[grp][g] : 0xFFFFFFFFu;
        int cLess = 0, cLeq = 0;
        for (int j = 0; j < w; j++) {
            const unsigned o = sbuf[grp][j];
            cLess += (o <  sv) ? 1 : 0;
            cLeq  += (o <= sv) ? 1 : 0;
        }
        unsigned cand = (g < w && cLess <= r && r < cLeq) ? sv : 0xFFFFFFFFu;
        #pragma unroll
        for (int m2 = 1; m2 < GG; m2 <<= 1)
            cand = min(cand, (unsigned)__shfl_xor((int)cand, m2));
        med = cand;
    }
    return med;
}

extern "C" __global__ void __launch_bounds__(NT, 8)
rec_fused(const float* __restrict__ emb, const float* __restrict__ ratings,
          const float* __restrict__ W1, const float* __restrict__ b1,
          const float* __restrict__ W2, const float* __restrict__ b2,
          const float* __restrict__ W3, const float* __restrict__ b3,
          const int* __restrict__ uidx, const int* __restrict__ lens,
          const int* __restrict__ midx, float* __restrict__ uo,
          float* __restrict__ out)
{
    __shared__ union US { ProdS p; ConsS c; } sm;
    const int bid = blockIdx.x;
    const int tid = threadIdx.x;

    if (bid < NB) {
        // ================= producer: R8 k1, byte-identical math ========
        const int b = bid;
        const int n = lens[b];
        const int k = (n - 1) >> 1;

        if (tid < EE) sm.p.scnt[tid] = 0;
        if (tid < n) {
            sm.p.idxL[tid] = uidx[b*LL + tid];
            sm.p.ratL[tid] = ratings[b*LL + tid];
        }
        __syncthreads();

        const int f = tid >> 3;   // feature id (0..63; active if < 50)
        const int g = tid & 7;

        // ---- gather chunk 1: l in [0, min(n,CH))
        const int c1 = (n < CH) ? n : CH;
        for (int p = tid; p < c1*(EE/2); p += NT) {
            const int l  = p / (EE/2);
            const int e2 = p - l*(EE/2);
            const float2 ev = ((const float2*)emb)[(size_t)sm.p.idxL[l]*(EE/2) + e2];
            const float  r  = sm.p.ratL[l];
            sm.p.wK[2*e2    ][l] = f2key(ev.x * r);
            sm.p.wK[2*e2 + 1][l] = f2key(ev.y * r);
        }
        __syncthreads();

        // ---- distribute chunk 1 (fixed t-order => bit-exact stats)
        unsigned it[IT];
        unsigned kmin = 0xFFFFFFFFu, kmax = 0u;
        float smm = 0.f;
        if (f < EE) {
            #pragma unroll
            for (int t = 0; t < IT1; t++) {
                const int l = g + (t << 3);
                unsigned kk = 0xFFFFFFFFu;
                if (l < n) {
                    kk = sm.p.wK[f][l];
                    kmin = min(kmin, kk); kmax = max(kmax, kk);
                    smm += key2f(kk);
                }
                it[t] = kk;
            }
        }
        __syncthreads();          // chunk-1 reads done; tile reusable

        // ---- gather chunk 2: l in [CH, n)
        const int c2 = n - CH;    // may be <= 0
        for (int p = tid; p < c2*(EE/2); p += NT) {
            const int col = p / (EE/2);
            const int e2  = p - col*(EE/2);
            const int l   = CH + col;
            const float2 ev = ((const float2*)emb)[(size_t)sm.p.idxL[l]*(EE/2) + e2];
            const float  r  = sm.p.ratL[l];
            sm.p.wK[2*e2    ][col] = f2key(ev.x * r);
            sm.p.wK[2*e2 + 1][col] = f2key(ev.y * r);
        }
        __syncthreads();

        if (f < EE) {
            #pragma unroll
            for (int t = IT1; t < IT; t++) {
                const int l = g + (t << 3);
                unsigned kk = 0xFFFFFFFFu;
                if (l < n) {
                    kk = sm.p.wK[f][l - CH];
                    kmin = min(kmin, kk); kmax = max(kmax, kk);
                    smm += key2f(kk);
                }
                it[t] = kk;
            }
            #pragma unroll
            for (int m2 = 1; m2 < GG; m2 <<= 1) {
                kmin = min(kmin, (unsigned)__shfl_xor((int)kmin, m2));
                kmax = max(kmax, (unsigned)__shfl_xor((int)kmax, m2));
                smm += __shfl_xor(smm, m2);
            }

            const unsigned med = select_median(n, k, g, f, it, kmin, kmax,
                                               sm.p.sbuf, sm.p.scnt);
            if (g == 0) {
                float* ub = uo + (size_t)b * (4*EE);
                ub[f]        = key2f(kmin);
                ub[EE + f]   = key2f(kmax);
                ub[2*EE + f] = smm / (float)n;
                ub[3*EE + f] = key2f(med);
            }
        }
        __syncthreads();          // all uo stores drained (vmcnt in barrier)
        if (tid == 0)             // publish: release at device (agent) scope
            __hip_atomic_fetch_add(&g_done[b >> 4], 1,
                                   __ATOMIC_RELEASE, __HIP_MEMORY_SCOPE_AGENT);
    } else {
        // ================= consumer: R8 k2, W1 from global (L2-hot) ====
        const int j = bid - NB;

        // stage W2/biases while producers run (independent of uo)
        for (int p = tid; p < (2*EE*EE)/2; p += NT)
            ((float2*)sm.c.W2s)[p] = ((const float2*)W2)[p];
        if (tid < 2*EE) sm.c.b1s[tid] = b1[tid];
        if (tid < EE)   { sm.c.b2s[tid] = b2[tid]; sm.c.W3s[tid] = W3[tid]; }

        // wait for this group's 16 producers (acquire, agent scope)
        if (tid == 0) {
            while (__hip_atomic_load(&g_done[j], __ATOMIC_ACQUIRE,
                                     __HIP_MEMORY_SCOPE_AGENT) < BPB)
                __builtin_amdgcn_s_sleep(8);
        }
        __syncthreads();
        const float bias3 = b3[0];

        const int w    = tid >> 6;
        const int lane = tid & 63;

        #pragma unroll
        for (int rep = 0; rep < 2; rep++) {
            const int b = j * BPB + rep * 8 + w;

            // ---- load u row (coalesced), L2-norm via wave shuffle tree
            const float* ub = uo + (size_t)b * (4*EE);
            const float uv0 = ub[lane];
            const float uv1 = ub[lane + 64];
            const float uv2 = ub[lane + 128];
            const float uv3 = (lane < 4*EE - 192) ? ub[lane + 192] : 0.f;
            float v2 = uv0*uv0 + uv1*uv1 + uv2*uv2 + uv3*uv3;
            #pragma unroll
            for (int m2 = 1; m2 < 64; m2 <<= 1) v2 += __shfl_xor(v2, m2);
            const float inv = 1.0f / sqrtf(v2);

            // ---- x = [u/||u||, emb[movie]] into this wave's LDS row
            sm.c.xs[w][lane]       = uv0 * inv;
            sm.c.xs[w][lane + 64]  = uv1 * inv;
            sm.c.xs[w][lane + 128] = uv2 * inv;
            if (lane < 4*EE - 192) sm.c.xs[w][lane + 192] = uv3 * inv;
            if (lane < EE)
                sm.c.xs[w][4*EE + lane] = emb[(size_t)midx[b]*EE + lane];
            asm volatile("s_waitcnt lgkmcnt(0)" ::: "memory");  // wave RAW

            // ---- layer 1: lane owns o=lane and (lane<36) o+64;
            //      W1 rows from global: same lines every wave -> L1/L2-hot
            const int o2 = (lane + 64 < 2*EE) ? lane + 64 : 2*EE - 1;
            float a0 = 0.f, a1 = 0.f;
            #pragma unroll 5
            for (int i = 0; i < 5*EE; i++) {
                const float xv = sm.c.xs[w][i];      // LDS broadcast
                a0 += xv * W1[i*(2*EE) + lane];
                a1 += xv * W1[i*(2*EE) + o2];
            }
            const float h0  = fmaxf(a0 + sm.c.b1s[lane], 0.f);
            const float h64 = fmaxf(a1 + sm.c.b1s[o2],   0.f);
            sm.c.xs[w][lane] = h0;                   // reuse xs row for h1
            if (lane < 2*EE - 64) sm.c.xs[w][lane + 64] = h64;
            asm volatile("s_waitcnt lgkmcnt(0)" ::: "memory");

            // ---- layer 2 + output dot
            const int oc = (lane < EE) ? lane : EE - 1;
            float a2 = 0.f;
            #pragma unroll 5
            for (int i = 0; i < 2*EE; i++)
                a2 += sm.c.xs[w][i] * sm.c.W2s[i*EE + oc];
            const float h2v = fmaxf(a2 + sm.c.b2s[oc], 0.f);
            float v = (lane < EE) ? h2v * sm.c.W3s[lane] : 0.f;
            #pragma unroll
            for (int m2 = 1; m2 < 64; m2 <<= 1) v += __shfl_xor(v, m2);
            if (lane == 0) out[b] = 1.0f / (1.0f + expf(-(v + bias3)));
        }
    }
}

extern "C" void kernel_launch(void* const* d_in, const int* in_sizes, int n_in,
                              void* d_out, int out_size, void* d_ws, size_t ws_size,
                              hipStream_t stream) {
    const float* emb     = (const float*)d_in[0];
    const float* ratings = (const float*)d_in[1];
    const float* W1      = (const float*)d_in[2];
    const float* b1      = (const float*)d_in[3];
    const float* W2      = (const float*)d_in[4];
    const float* b2      = (const float*)d_in[5];
    const float* W3      = (const float*)d_in[6];
    const float* b3      = (const float*)d_in[7];
    const int*   uidx    = (const int*)d_in[8];
    const int*   lens    = (const int*)d_in[9];
    const int*   midx    = (const int*)d_in[10];
    float* out = (float*)d_out;
    float* uo  = (float*)d_ws;          // 4096*200*4 = 3.28 MB raw stats

    static void* gsym = nullptr;        // cached device-symbol address
    if (!gsym) hipGetSymbolAddress(&gsym, HIP_SYMBOL(g_done));
    hipMemsetAsync(gsym, 0, sizeof(int) * K2B, stream);   // re-arm counters

    hipLaunchKernelGGL(rec_fused, dim3(NB + K2B), dim3(NT), 0, stream,
                       emb, ratings, W1, b1, W2, b2, W3, b3,
                       uidx, lens, midx, uo, out);
}

// Round 15
// 93.219 us; speedup vs baseline: 2.0462x; 2.0462x over previous
//
#include <hip/hip_runtime.h>
#include <math.h>

#define NB 4096     // B
#define LL 200      // L
#define EE 50       // E
#define CH 104      // gather chunk-1 length (13*8); chunk-2 = 96
#define CP 105      // chunk tile stride in words (odd -> spread banks)
#define NT 512      // k1 threads (8 waves)
#define GG 8        // lanes per feature group
#define IT 25       // items per lane in registers
#define IT1 13      // chunk-1 covers t in [0,13), l = g+8t < 104
#define SW 8        // small-set threshold

#define K2B 256     // k2 blocks
#define K2T 512     // k2 threads (8 waves)
#define BPB 16      // batches per k2 block (2 reps x 8 waves)

// monotonic float -> sortable uint32 (order-preserving bijection)
__device__ __forceinline__ unsigned f2key(float f) {
    unsigned b = __float_as_uint(f);
    unsigned mask = (b & 0x80000000u) ? 0xFFFFFFFFu : 0x80000000u;
    return b ^ mask;
}
__device__ __forceinline__ float key2f(unsigned kk) {
    unsigned mask = (kk & 0x80000000u) ? 0x80000000u : 0xFFFFFFFFu;
    return __uint_as_float(kk ^ mask);
}

// exact interpolation-select (invariant: cLO=#{x<LO} <= k < cHI=#{x<HI})
__device__ __forceinline__ unsigned select_median(
    int n, int k, int g, int grp, const unsigned it[IT],
    unsigned kmin, unsigned kmax, unsigned (*sbuf)[SW], int *scnt)
{
    unsigned LO = kmin, HI = kmax + 1u;   // finite keys: no wrap
    int cLO = 0, cHI = n;
    unsigned med = 0u;
    bool small = false;
    int pass = 0;
    for (;;) {
        if (HI - LO == 1u) { med = LO; break; }   // window collapsed
        const int w = cHI - cLO;
        if (w <= SW) { small = true; break; }
        unsigned P;
        if (pass < 8) {            // float-space interpolation pivot
            const float vlo = key2f(LO);
            const float vhi = key2f(HI - 1u);
            const float frac = (float)(k - cLO + 1) / (float)(w + 1);
            P = f2key(vlo + (vhi - vlo) * frac);
        } else {                   // guaranteed-progress bisection
            P = LO + ((HI - LO) >> 1);
        }
        if (P <= LO) P = LO + 1u;  // strict interior: interval shrinks
        if (P >= HI) P = HI - 1u;
        int c = 0;                 // #{x < P}; sentinels never count
        #pragma unroll
        for (int t = 0; t < IT; t++) c += (it[t] < P) ? 1 : 0;
        c += __shfl_xor(c, 1);
        c += __shfl_xor(c, 2);
        c += __shfl_xor(c, 4);
        if (c > k) { HI = P; cHI = c; }
        else       { LO = P; cLO = c; }
        pass++;
    }
    if (small) {
        const int w = cHI - cLO;   // #survivors, <= SW
        const int r = k - cLO;     // target rank among survivors
        #pragma unroll
        for (int t = 0; t < IT; t++) {
            const unsigned kk = it[t];
            if (kk >= LO && kk < HI) {
                const int pos = atomicAdd(&scnt[grp], 1);
                if (pos < SW) sbuf[grp][pos] = kk;
            }
        }
        // same-wave LDS ordering: compiler lgkmcnt waits cover these reads
        const unsigned sv = (g < w) ? sbuf[grp][g] : 0xFFFFFFFFu;
        int cLess = 0, cLeq = 0;
        for (int j = 0; j < w; j++) {
            const unsigned o = sbuf[grp][j];
            cLess += (o <  sv) ? 1 : 0;
            cLeq  += (o <= sv) ? 1 : 0;
        }
        unsigned cand = (g < w && cLess <= r && r < cLeq) ? sv : 0xFFFFFFFFu;
        #pragma unroll
        for (int m2 = 1; m2 < GG; m2 <<= 1)
            cand = min(cand, (unsigned)__shfl_xor((int)cand, m2));
        med = cand;
    }
    return med;
}

// ================= kernel 1: pooled stats -> workspace =================
extern "C" __global__ void __launch_bounds__(NT, 8)
rec_stats(const float* __restrict__ emb, const float* __restrict__ ratings,
          const int* __restrict__ uidx, const int* __restrict__ lens,
          float* __restrict__ uo)
{
    __shared__ unsigned wK[EE][CP];     // 21 KB chunked key tile
    __shared__ int      idxL[LL];
    __shared__ float    ratL[LL];
    __shared__ unsigned sbuf[EE][SW];
    __shared__ int      scnt[EE];

    const int b   = blockIdx.x;
    const int tid = threadIdx.x;
    const int n   = lens[b];
    const int k   = (n - 1) >> 1;

    if (tid < EE) scnt[tid] = 0;
    if (tid < n) {
        idxL[tid] = uidx[b*LL + tid];
        ratL[tid] = ratings[b*LL + tid];
    }
    __syncthreads();

    const int f = tid >> 3;   // feature id (0..63; active if < 50)
    const int g = tid & 7;

    // ---- gather chunk 1: l in [0, min(n,CH))
    const int c1 = (n < CH) ? n : CH;
    for (int p = tid; p < c1*(EE/2); p += NT) {
        const int l  = p / (EE/2);
        const int e2 = p - l*(EE/2);
        const float2 ev = ((const float2*)emb)[(size_t)idxL[l]*(EE/2) + e2];
        const float  r  = ratL[l];
        wK[2*e2    ][l] = f2key(ev.x * r);
        wK[2*e2 + 1][l] = f2key(ev.y * r);
    }
    __syncthreads();

    // ---- distribute chunk 1 (t-order identical to R4 => bit-exact stats)
    unsigned it[IT];
    unsigned kmin = 0xFFFFFFFFu, kmax = 0u;
    float sm = 0.f;
    if (f < EE) {
        #pragma unroll
        for (int t = 0; t < IT1; t++) {
            const int l = g + (t << 3);
            unsigned kk = 0xFFFFFFFFu;
            if (l < n) {
                kk = wK[f][l];
                kmin = min(kmin, kk); kmax = max(kmax, kk); sm += key2f(kk);
            }
            it[t] = kk;
        }
    }
    __syncthreads();          // chunk-1 reads done; tile reusable

    // ---- gather chunk 2: l in [CH, n)
    const int c2 = n - CH;    // may be <= 0
    for (int p = tid; p < c2*(EE/2); p += NT) {
        const int col = p / (EE/2);
        const int e2  = p - col*(EE/2);
        const int l   = CH + col;
        const float2 ev = ((const float2*)emb)[(size_t)idxL[l]*(EE/2) + e2];
        const float  r  = ratL[l];
        wK[2*e2    ][col] = f2key(ev.x * r);
        wK[2*e2 + 1][col] = f2key(ev.y * r);
    }
    __syncthreads();

    if (f < EE) {
        #pragma unroll
        for (int t = IT1; t < IT; t++) {
            const int l = g + (t << 3);
            unsigned kk = 0xFFFFFFFFu;
            if (l < n) {
                kk = wK[f][l - CH];
                kmin = min(kmin, kk); kmax = max(kmax, kk); sm += key2f(kk);
            }
            it[t] = kk;
        }
        #pragma unroll
        for (int m2 = 1; m2 < GG; m2 <<= 1) {
            kmin = min(kmin, (unsigned)__shfl_xor((int)kmin, m2));
            kmax = max(kmax, (unsigned)__shfl_xor((int)kmax, m2));
            sm  += __shfl_xor(sm, m2);
        }

        const unsigned med = select_median(n, k, g, f, it, kmin, kmax,
                                           sbuf, scnt);
        if (g == 0) {
            float* ub = uo + (size_t)b * (4*EE);
            ub[f]        = key2f(kmin);
            ub[EE + f]   = key2f(kmax);
            ub[2*EE + f] = sm / (float)n;
            ub[3*EE + f] = key2f(med);
        }
    }
}

// ================= kernel 2: norm + MLP (weights in LDS) =================
extern "C" __global__ void __launch_bounds__(K2T, 2)
rec_mlp(const float* __restrict__ emb,
        const float* __restrict__ W1, const float* __restrict__ b1,
        const float* __restrict__ W2, const float* __restrict__ b2,
        const float* __restrict__ W3, const float* __restrict__ b3,
        const int* __restrict__ midx, const float* __restrict__ uo,
        float* __restrict__ out)
{
    __shared__ float W1s[5*EE * 2*EE];   // 100 KB
    __shared__ float W2s[2*EE * EE];     // 20 KB
    __shared__ float b1s[2*EE];
    __shared__ float b2s[EE];
    __shared__ float W3s[EE];
    __shared__ float xs[8][252];         // per-wave x / h1 scratch

    const int tid = threadIdx.x;

    // ---- stage weights once per block (float2 coalesced)
    for (int p = tid; p < (5*EE*2*EE)/2; p += K2T)
        ((float2*)W1s)[p] = ((const float2*)W1)[p];
    for (int p = tid; p < (2*EE*EE)/2; p += K2T)
        ((float2*)W2s)[p] = ((const float2*)W2)[p];
    if (tid < 2*EE) b1s[tid] = b1[tid];
    if (tid < EE)   { b2s[tid] = b2[tid]; W3s[tid] = W3[tid]; }
    __syncthreads();
    const float bias3 = b3[0];

    const int w    = tid >> 6;
    const int lane = tid & 63;

    #pragma unroll
    for (int rep = 0; rep < 2; rep++) {
        const int b = blockIdx.x * BPB + rep * 8 + w;

        // ---- load u row (coalesced), L2-norm via wave shuffle tree
        float uv0 = 0.f, uv1 = 0.f, uv2 = 0.f, uv3 = 0.f;
        const float* ub = uo + (size_t)b * (4*EE);
        uv0 = ub[lane];
        uv1 = ub[lane + 64];
        uv2 = ub[lane + 128];
        if (lane < 4*EE - 192) uv3 = ub[lane + 192];
        float v2 = uv0*uv0 + uv1*uv1 + uv2*uv2 + uv3*uv3;
        #pragma unroll
        for (int m2 = 1; m2 < 64; m2 <<= 1) v2 += __shfl_xor(v2, m2);
        const float inv = 1.0f / sqrtf(v2);

        // ---- x = [u/||u||, emb[movie]] into this wave's LDS row
        xs[w][lane]       = uv0 * inv;
        xs[w][lane + 64]  = uv1 * inv;
        xs[w][lane + 128] = uv2 * inv;
        if (lane < 4*EE - 192) xs[w][lane + 192] = uv3 * inv;
        if (lane < EE) xs[w][4*EE + lane] = emb[(size_t)midx[b]*EE + lane];
        asm volatile("s_waitcnt lgkmcnt(0)" ::: "memory");  // wave-local RAW

        // ---- layer 1: lane owns outputs o=lane and (lane<36) o+64
        const int o2 = (lane + 64 < 2*EE) ? lane + 64 : 2*EE - 1;
        float a0 = 0.f, a1 = 0.f;
        #pragma unroll 5
        for (int i = 0; i < 5*EE; i++) {
            const float xv = xs[w][i];              // LDS broadcast
            a0 += xv * W1s[i*(2*EE) + lane];
            a1 += xv * W1s[i*(2*EE) + o2];
        }
        const float h0  = fmaxf(a0 + b1s[lane], 0.f);
        const float h64 = fmaxf(a1 + b1s[o2],   0.f);
        // h1 -> reuse xs row (x is dead; same-wave ordering via waitcnt)
        xs[w][lane] = h0;
        if (lane < 2*EE - 64) xs[w][lane + 64] = h64;
        asm volatile("s_waitcnt lgkmcnt(0)" ::: "memory");

        // ---- layer 2 + output dot
        const int oc = (lane < EE) ? lane : EE - 1;
        float a2 = 0.f;
        #pragma unroll 5
        for (int i = 0; i < 2*EE; i++)
            a2 += xs[w][i] * W2s[i*EE + oc];
        const float h2v = fmaxf(a2 + b2s[oc], 0.f);
        float v = (lane < EE) ? h2v * W3s[lane] : 0.f;
        #pragma unroll
        for (int m2 = 1; m2 < 64; m2 <<= 1) v += __shfl_xor(v, m2);
        if (lane == 0) out[b] = 1.0f / (1.0f + expf(-(v + bias3)));
    }
}

extern "C" void kernel_launch(void* const* d_in, const int* in_sizes, int n_in,
                              void* d_out, int out_size, void* d_ws, size_t ws_size,
                              hipStream_t stream) {
    const float* emb     = (const float*)d_in[0];
    const float* ratings = (const float*)d_in[1];
    const float* W1      = (const float*)d_in[2];
    const float* b1      = (const float*)d_in[3];
    const float* W2      = (const float*)d_in[4];
    const float* b2      = (const float*)d_in[5];
    const float* W3      = (const float*)d_in[6];
    const float* b3      = (const float*)d_in[7];
    const int*   uidx    = (const int*)d_in[8];
    const int*   lens    = (const int*)d_in[9];
    const int*   midx    = (const int*)d_in[10];
    float* out = (float*)d_out;
    float* uo  = (float*)d_ws;          // 4096*200*4 = 3.28 MB raw stats

    hipLaunchKernelGGL(rec_stats, dim3(NB), dim3(NT), 0, stream,
                       emb, ratings, uidx, lens, uo);
    hipLaunchKernelGGL(rec_mlp, dim3(K2B), dim3(K2T), 0, stream,
                       emb, W1, b1, W2, b2, W3, b3, midx, uo, out);
}